// Round 7
// baseline (180.656 us; speedup 1.0000x reference)
//
#include <hip/hip_runtime.h>
#include <stdint.h>
#include <math.h>

#define TK 256
#define TT 256
#define DD 64
#define HH 256
#define PAD 68          // LDS row stride in floats
#define NTHREADS 1024
#define JPT 64          // j's per thread

// ---- exact JAX threefry2x32 (key = (0,42), 20 rounds) ----
__device__ __forceinline__ uint32_t rotl32(uint32_t x, uint32_t d) {
  return (x << d) | (x >> (32u - d));
}

__device__ __forceinline__ uint2 threefry2x32(uint32_t x0, uint32_t x1) {
  const uint32_t ks0 = 0u, ks1 = 42u, ks2 = 0x1BD11BDAu ^ 0u ^ 42u; // 0x1BD11BF0
  x0 += ks0; x1 += ks1;
#define TFR(r) { x0 += x1; x1 = rotl32(x1, r); x1 ^= x0; }
  TFR(13u) TFR(15u) TFR(26u) TFR(6u)
  x0 += ks1; x1 += ks2 + 1u;
  TFR(17u) TFR(29u) TFR(16u) TFR(24u)
  x0 += ks2; x1 += ks0 + 2u;
  TFR(13u) TFR(15u) TFR(26u) TFR(6u)
  x0 += ks0; x1 += ks1 + 3u;
  TFR(17u) TFR(29u) TFR(16u) TFR(24u)
  x0 += ks1; x1 += ks2 + 4u;
  TFR(13u) TFR(15u) TFR(26u) TFR(6u)
  x0 += ks2; x1 += ks0 + 5u;
#undef TFR
  return make_uint2(x0, x1);
}

__global__ __launch_bounds__(NTHREADS) void ep_fused(
    const int*   __restrict__ pN,
    const int*   __restrict__ leaf,   // [K][T] int32
    const float* __restrict__ emb,    // [K][T][D]
    const float* __restrict__ W1,     // [2D][H]
    const float* __restrict__ b1,     // [H]
    const float* __restrict__ W2,     // [H][D]
    const float* __restrict__ b2,     // [D]
    float*       __restrict__ out)
{
  __shared__ float s_emb[TT * PAD];   // 69632 B
  __shared__ float s_sq[TT];
  __shared__ float s_wss[16];
  __shared__ float s_wb[16];
  __shared__ int   s_wi[16];
  __shared__ float s_h[HH];
  __shared__ float s_e[DD];
  __shared__ int   s_onesw[16];
  __shared__ int   s_sel[2];
  __shared__ float s_lse;

  const int k   = blockIdx.x;
  const int tid = threadIdx.x;
  const int i   = tid & 255;             // row this thread owns
  const int jbase = (tid >> 8) * JPT;    // quarter of j-range

  const float* ek = emb + (size_t)k * (TT * DD);

  // stage emb_k into LDS (coalesced float4)
  for (int idx = tid; idx < TT * DD / 4; idx += NTHREADS) {
    float4 v = ((const float4*)ek)[idx];
    int f = idx << 2;
    int r = f >> 6, c = f & 63;
    *(float4*)&s_emb[r * PAD + c] = v;
  }
  __syncthreads();

  // sq[i] = sum(emb_i^2)
  if (tid < TT) {
    const float* row = &s_emb[tid * PAD];
    float acc = 0.f;
#pragma unroll
    for (int c = 0; c < DD; ++c) acc = fmaf(row[c], row[c], acc);
    s_sq[tid] = acc;
  }
  __syncthreads();

  // own row into registers — asm fence makes each value opaque so the
  // compiler CANNOT rematerialize these as per-FMA LDS reads (R5: VGPR=48
  // proved a[] was living in LDS, saturating the LDS pipe).
  float a[DD];
  {
    const float* row = &s_emb[i * PAD];
#pragma unroll
    for (int c = 0; c < DD; ++c) a[c] = row[c];
#pragma unroll
    for (int c = 0; c < DD; ++c) asm volatile("" : "+v"(a[c]));
  }
  const float sqi = s_sq[i];

  // PARTITIONABLE threefry: counter (0, p), bits = b1 ^ b2 (verified R4)
  const uint32_t pb = ((uint32_t)k << 16) | ((uint32_t)i << 8);

  // fixed-shift LSE (all logits <= 0, so m=0 is overflow-safe)
  float ss = 0.f;
  float best = -3.402823466e38f; int bj = jbase;

  for (int j = jbase; j < jbase + JPT; ++j) {
    const float4* b4p = (const float4*)&s_emb[j * PAD];   // wave-uniform broadcast
    float d0 = 0.f, d1 = 0.f, d2a = 0.f, d3 = 0.f;
#pragma unroll
    for (int c4 = 0; c4 < 16; ++c4) {
      float4 b4 = b4p[c4];
      d0  = fmaf(a[c4 * 4 + 0], b4.x, d0);
      d1  = fmaf(a[c4 * 4 + 1], b4.y, d1);
      d2a = fmaf(a[c4 * 4 + 2], b4.z, d2a);
      d3  = fmaf(a[c4 * 4 + 3], b4.w, d3);
    }
    float dot = (d0 + d1) + (d2a + d3);
    float dsq = sqi + s_sq[j] - 2.0f * dot;
    float lw  = -sqrtf(fmaxf(dsq, 0.f));
    if (j != i) {
      ss += __expf(lw);
      // exact JAX gumbel bits; fast log for selection-only value
      uint2 r = threefry2x32(0u, pb + (uint32_t)j);
      uint32_t bits = r.x ^ r.y;
      float f = __uint_as_float((bits >> 9) | 0x3F800000u) - 1.0f;  // [0,1)
      float u = fmaxf(f, 1.1754943508222875e-38f);                  // minval=tiny
      float g = -__logf(-__logf(u));
      float sv = lw + g;
      if (sv > best) { best = sv; bj = j; }   // strict > keeps first occurrence
    }
  }

  // per-wave butterfly reductions (width 64)
  int bidx = i * TT + bj;
#pragma unroll
  for (int off = 32; off > 0; off >>= 1) {
    ss += __shfl_xor(ss, off);
    float ob = __shfl_xor(best, off);
    int   oi = __shfl_xor(bidx, off);
    if (ob > best || (ob == best && oi < bidx)) { best = ob; bidx = oi; }
  }
  {
    int lane = tid & 63, wv = tid >> 6;
    if (lane == 0) { s_wss[wv] = ss; s_wb[wv] = best; s_wi[wv] = bidx; }
  }
  // count leaf_counts==1 via per-wave ballot
  {
    int lane = tid & 63, wv = tid >> 6;
    int isone = (tid < TT) ? ((leaf[k * TT + tid] == 1) ? 1 : 0) : 0;
    unsigned long long bal = __ballot(isone);
    if (lane == 0) s_onesw[wv] = __popcll(bal);
  }
  __syncthreads();

  if (tid == 0) {
    float tot = 0.f, bb = -3.402823466e38f; int bi = 0x7fffffff;
    for (int w = 0; w < 16; ++w) {
      tot += s_wss[w];
      if (s_wb[w] > bb || (s_wb[w] == bb && s_wi[w] < bi)) { bb = s_wb[w]; bi = s_wi[w]; }
    }
    s_sel[0] = bi >> 8;       // idx1
    s_sel[1] = bi & 255;      // idx2
    s_lse    = logf(tot);     // accurate log, once
  }
  __syncthreads();

  const int i1 = s_sel[0], i2 = s_sel[1];
  const float* c1 = &s_emb[i1 * PAD];
  const float* c2 = &s_emb[i2 * PAD];

  // h = relu([c1,c2] @ W1 + b1); W1 reads are lane-coalesced
  if (tid < HH) {
    float h0 = 0.f, h1 = 0.f;
#pragma unroll 8
    for (int c = 0; c < DD; ++c) h0 = fmaf(c1[c], W1[c * HH + tid], h0);
#pragma unroll 8
    for (int c = 0; c < DD; ++c) h1 = fmaf(c2[c], W1[(DD + c) * HH + tid], h1);
    s_h[tid] = fmaxf(h0 + h1 + b1[tid], 0.f);
  }
  __syncthreads();

  // e = h @ W2 + b2
  if (tid < DD) {
    float acc = 0.f;
#pragma unroll 8
    for (int hh = 0; hh < HH; ++hh) acc = fmaf(s_h[hh], W2[hh * DD + tid], acc);
    float e = acc + b2[tid];
    s_e[tid] = e;
    out[1024 + k * DD + tid] = e;          // embedding_KxD
  }
  __syncthreads();

  // branch lengths: ||c - e|| via wave-0 butterfly
  if (tid < DD) {
    float dd1 = c1[tid] - s_e[tid];
    float dd2 = c2[tid] - s_e[tid];
    float q1 = dd1 * dd1, q2 = dd2 * dd2;
#pragma unroll
    for (int off = 32; off > 0; off >>= 1) {
      q1 += __shfl_xor(q1, off);
      q2 += __shfl_xor(q2, off);
    }
    if (tid == 0) {
      out[512 + k] = sqrtf(q1);            // branch1_K
      out[768 + k] = sqrtf(q2);            // branch2_K
    }
  }

  if (tid == 0) {
    // recompute logw at the selected pair
    float dot = 0.f;
#pragma unroll
    for (int c = 0; c < DD; ++c) dot = fmaf(c1[c], c2[c], dot);
    float dsq = s_sq[i1] + s_sq[i2] - 2.0f * dot;
    float lw  = -sqrtf(fmaxf(dsq, 0.f));
    out[0   + k] = (float)i1;              // idx1_K
    out[256 + k] = (float)i2;              // idx2_K
    out[17408 + k] = lw + 0.69314718055994531f - s_lse;   // log_v_plus_K
    int ones = 0;
    for (int w = 0; w < 16; ++w) ones += s_onesw[w];
    ones -= (leaf[k * TT + i1] == 1) ? 1 : 0;
    ones -= (leaf[k * TT + i2] == 1) ? 1 : 0;
    int vminus = pN[0] - ones;
    out[17664 + k] = logf((float)vminus);  // log_v_minus_K
  }
}

extern "C" void kernel_launch(void* const* d_in, const int* in_sizes, int n_in,
                              void* d_out, int out_size, void* d_ws, size_t ws_size,
                              hipStream_t stream) {
  const int*   pN   = (const int*)d_in[0];
  const int*   leaf = (const int*)d_in[1];
  const float* emb  = (const float*)d_in[2];
  // d_in[3] = "log" scalar, unused
  const float* W1   = (const float*)d_in[4];
  const float* b1   = (const float*)d_in[5];
  const float* W2   = (const float*)d_in[6];
  const float* b2   = (const float*)d_in[7];
  float* out = (float*)d_out;

  ep_fused<<<TK, NTHREADS, 0, stream>>>(pN, leaf, emb, W1, b1, W2, b2, out);
}

// Round 11
// 158.005 us; speedup vs baseline: 1.1434x; 1.1434x over previous
//
#include <hip/hip_runtime.h>
#include <stdint.h>
#include <math.h>

#define TK 256
#define TT 256
#define DD 64
#define HH 256
#define NTHREADS 1024
#define PADB 72   // bf16 row stride (144 B): 16-lane frag reads alias 2-way (free, m136)

typedef short bf16x8 __attribute__((ext_vector_type(8)));
typedef float f32x4  __attribute__((ext_vector_type(4)));

// ---- exact JAX threefry2x32 (key=(0,42)); partitionable: ctr=(0,p), bits=x^y (R4-verified)
__device__ __forceinline__ uint32_t rotl32(uint32_t x, uint32_t d) {
  return (x << d) | (x >> (32u - d));
}
__device__ __forceinline__ uint2 threefry2x32(uint32_t x0, uint32_t x1) {
  const uint32_t ks0 = 0u, ks1 = 42u, ks2 = 0x1BD11BF0u;
  x0 += ks0; x1 += ks1;
#define TFR(r) { x0 += x1; x1 = rotl32(x1, r); x1 ^= x0; }
  TFR(13u) TFR(15u) TFR(26u) TFR(6u)
  x0 += ks1; x1 += ks2 + 1u;
  TFR(17u) TFR(29u) TFR(16u) TFR(24u)
  x0 += ks2; x1 += ks0 + 2u;
  TFR(13u) TFR(15u) TFR(26u) TFR(6u)
  x0 += ks0; x1 += ks1 + 3u;
  TFR(17u) TFR(29u) TFR(16u) TFR(24u)
  x0 += ks1; x1 += ks2 + 4u;
  TFR(13u) TFR(15u) TFR(26u) TFR(6u)
  x0 += ks2; x1 += ks0 + 5u;
#undef TFR
  return make_uint2(x0, x1);
}

__device__ __forceinline__ uint16_t f2bf(float x) {   // RNE bf16 (no NaN in data)
  uint32_t u = __float_as_uint(x);
  return (uint16_t)((u + 0x7FFFu + ((u >> 16) & 1u)) >> 16);
}

__global__ __launch_bounds__(NTHREADS) void ep_fused(
    const int*   __restrict__ pN,
    const int*   __restrict__ leaf,   // [K][T]
    const float* __restrict__ emb,    // [K][T][D]
    const float* __restrict__ W1,     // [2D][H]
    const float* __restrict__ b1,
    const float* __restrict__ W2,     // [H][D]
    const float* __restrict__ b2,
    float*       __restrict__ out)
{
  __shared__ uint16_t s_hi[TT * PADB];   // 36864 B
  __shared__ uint16_t s_lo[TT * PADB];   // 36864 B
  __shared__ float s_sq[TT];
  __shared__ float s_c1[DD], s_c2[DD];
  __shared__ float s_wss[16], s_wb[16];
  __shared__ int   s_wi[16], s_onesw[16], s_sel[2];
  __shared__ float s_h[HH], s_e[DD];
  __shared__ float s_lse;

  const int k   = blockIdx.x;
  const int tid = threadIdx.x;
  const float* ek = emb + (size_t)k * (TT * DD);

  // ---- stage: fp32 global -> bf16 hi/lo split in LDS (coalesced float4) ----
  for (int idx = tid; idx < TT * DD / 4; idx += NTHREADS) {
    float4 v = ((const float4*)ek)[idx];
    int f = idx << 2;
    int r = f >> 6, c = f & 63;
    uint16_t h0 = f2bf(v.x), h1 = f2bf(v.y), h2 = f2bf(v.z), h3 = f2bf(v.w);
    float l0f = v.x - __uint_as_float((uint32_t)h0 << 16);
    float l1f = v.y - __uint_as_float((uint32_t)h1 << 16);
    float l2f = v.z - __uint_as_float((uint32_t)h2 << 16);
    float l3f = v.w - __uint_as_float((uint32_t)h3 << 16);
    uint2 hp = make_uint2((uint32_t)h0 | ((uint32_t)h1 << 16),
                          (uint32_t)h2 | ((uint32_t)h3 << 16));
    uint2 lp = make_uint2((uint32_t)f2bf(l0f) | ((uint32_t)f2bf(l1f) << 16),
                          (uint32_t)f2bf(l2f) | ((uint32_t)f2bf(l3f) << 16));
    *(uint2*)&s_hi[r * PADB + c] = hp;
    *(uint2*)&s_lo[r * PADB + c] = lp;
  }
  // exact fp32 row norms straight from global (L2-resident, one-time)
  if (tid < TT) {
    const float* row = ek + tid * DD;
    float acc = 0.f;
#pragma unroll
    for (int c = 0; c < DD; ++c) acc = fmaf(row[c], row[c], acc);
    s_sq[tid] = acc;
  }
  __syncthreads();

  // ---- MFMA Gram + per-element threefry/gumbel/argmax/LSE ----
  const int wv = tid >> 6, l = tid & 63;
  const int lm = l & 15, lk = l >> 4;
  const int I0 = wv * 16;                     // this wave's i-tile (16 waves x 16 rows)

  // A-fragments: lane holds A[m=lm][k=lk*8+r], ks in {0,1} covers K=64. Loaded once.
  const char* hib = (const char*)s_hi;
  const char* lob = (const char*)s_lo;
  const int arow = (I0 + lm) * (PADB * 2);
  bf16x8 ah0 = *(const bf16x8*)(hib + arow + lk * 16);
  bf16x8 ah1 = *(const bf16x8*)(hib + arow + 64 + lk * 16);
  bf16x8 al0 = *(const bf16x8*)(lob + arow + lk * 16);
  bf16x8 al1 = *(const bf16x8*)(lob + arow + 64 + lk * 16);

  float sqi_r[4];
#pragma unroll
  for (int r = 0; r < 4; ++r) sqi_r[r] = s_sq[I0 + lk * 4 + r];

  float ss = 0.f, best = -3.402823466e38f;
  int bidx = 0x7fffffff;

  for (int jt = 0; jt < 16; ++jt) {
    const int J0 = jt * 16;
    const int brow = (J0 + lm) * (PADB * 2);
    bf16x8 bh0 = *(const bf16x8*)(hib + brow + lk * 16);
    bf16x8 bh1 = *(const bf16x8*)(hib + brow + 64 + lk * 16);
    bf16x8 bl0 = *(const bf16x8*)(lob + brow + lk * 16);
    bf16x8 bl1 = *(const bf16x8*)(lob + brow + 64 + lk * 16);

    f32x4 acc = {0.f, 0.f, 0.f, 0.f};
    acc = __builtin_amdgcn_mfma_f32_16x16x32_bf16(ah0, bh0, acc, 0, 0, 0);
    acc = __builtin_amdgcn_mfma_f32_16x16x32_bf16(ah0, bl0, acc, 0, 0, 0);
    acc = __builtin_amdgcn_mfma_f32_16x16x32_bf16(al0, bh0, acc, 0, 0, 0);
    acc = __builtin_amdgcn_mfma_f32_16x16x32_bf16(ah1, bh1, acc, 0, 0, 0);
    acc = __builtin_amdgcn_mfma_f32_16x16x32_bf16(ah1, bl1, acc, 0, 0, 0);
    acc = __builtin_amdgcn_mfma_f32_16x16x32_bf16(al1, bh1, acc, 0, 0, 0);

    const int j = J0 + lm;                    // C/D: col = lane&15 (m89-verified)
    const float sqj = s_sq[j];
    const uint32_t pbase = ((uint32_t)k << 16) | (uint32_t)j;

#pragma unroll
    for (int r = 0; r < 4; ++r) {             // C/D: row = (lane>>4)*4 + r
      const int i = I0 + lk * 4 + r;
      float dsq = sqi_r[r] + sqj - 2.0f * acc[r];
      float lw  = -sqrtf(fmaxf(dsq, 0.f));
      if (i != j) {
        ss += __expf(lw);
        uint2 rr = threefry2x32(0u, pbase + ((uint32_t)i << 8));
        uint32_t bits = rr.x ^ rr.y;
        float f = __uint_as_float((bits >> 9) | 0x3F800000u) - 1.0f;
        float u = fmaxf(f, 1.1754943508222875e-38f);
        float g = -__logf(-__logf(u));
        float sv = lw + g;
        int fi = i * TT + j;
        if (sv > best || (sv == best && fi < bidx)) { best = sv; bidx = fi; }
      }
    }
  }

  // ---- wave butterfly + cross-wave reduction (unchanged from R5) ----
#pragma unroll
  for (int off = 32; off > 0; off >>= 1) {
    ss += __shfl_xor(ss, off);
    float ob = __shfl_xor(best, off);
    int   oi = __shfl_xor(bidx, off);
    if (ob > best || (ob == best && oi < bidx)) { best = ob; bidx = oi; }
  }
  if (l == 0) { s_wss[wv] = ss; s_wb[wv] = best; s_wi[wv] = bidx; }
  {
    int isone = (tid < TT) ? ((leaf[k * TT + tid] == 1) ? 1 : 0) : 0;
    unsigned long long bal = __ballot(isone);
    if (l == 0) s_onesw[wv] = __popcll(bal);
  }
  __syncthreads();

  if (tid == 0) {
    float tot = 0.f, bb = -3.402823466e38f; int bi = 0x7fffffff;
    for (int w = 0; w < 16; ++w) {
      tot += s_wss[w];
      if (s_wb[w] > bb || (s_wb[w] == bb && s_wi[w] < bi)) { bb = s_wb[w]; bi = s_wi[w]; }
    }
    s_sel[0] = bi >> 8;
    s_sel[1] = bi & 255;
    s_lse    = logf(tot);
  }
  __syncthreads();

  const int i1 = s_sel[0], i2 = s_sel[1];
  // exact fp32 child rows from global
  if (tid < DD) {
    s_c1[tid] = ek[i1 * DD + tid];
    s_c2[tid] = ek[i2 * DD + tid];
  }
  __syncthreads();

  // h = relu([c1,c2] @ W1 + b1)
  if (tid < HH) {
    float h0 = 0.f, h1 = 0.f;
#pragma unroll 8
    for (int c = 0; c < DD; ++c) h0 = fmaf(s_c1[c], W1[c * HH + tid], h0);
#pragma unroll 8
    for (int c = 0; c < DD; ++c) h1 = fmaf(s_c2[c], W1[(DD + c) * HH + tid], h1);
    s_h[tid] = fmaxf(h0 + h1 + b1[tid], 0.f);
  }
  __syncthreads();

  // e = h @ W2 + b2
  if (tid < DD) {
    float acc = 0.f;
#pragma unroll 8
    for (int hh = 0; hh < HH; ++hh) acc = fmaf(s_h[hh], W2[hh * DD + tid], acc);
    float e = acc + b2[tid];
    s_e[tid] = e;
    out[1024 + k * DD + tid] = e;          // embedding_KxD
  }
  __syncthreads();

  // branch lengths via wave-0 butterfly
  if (tid < DD) {
    float dd1 = s_c1[tid] - s_e[tid];
    float dd2 = s_c2[tid] - s_e[tid];
    float q1 = dd1 * dd1, q2 = dd2 * dd2;
#pragma unroll
    for (int off = 32; off > 0; off >>= 1) {
      q1 += __shfl_xor(q1, off);
      q2 += __shfl_xor(q2, off);
    }
    if (tid == 0) {
      out[512 + k] = sqrtf(q1);            // branch1_K
      out[768 + k] = sqrtf(q2);            // branch2_K
    }
  }

  if (tid == 0) {
    // exact fp32 logw at the selected pair
    float dot = 0.f;
#pragma unroll
    for (int c = 0; c < DD; ++c) dot = fmaf(s_c1[c], s_c2[c], dot);
    float dsq = s_sq[i1] + s_sq[i2] - 2.0f * dot;
    float lw  = -sqrtf(fmaxf(dsq, 0.f));
    out[0   + k] = (float)i1;              // idx1_K
    out[256 + k] = (float)i2;              // idx2_K
    out[17408 + k] = lw + 0.69314718055994531f - s_lse;   // log_v_plus_K
    int ones = 0;
    for (int w = 0; w < 16; ++w) ones += s_onesw[w];
    ones -= (leaf[k * TT + i1] == 1) ? 1 : 0;
    ones -= (leaf[k * TT + i2] == 1) ? 1 : 0;
    int vminus = pN[0] - ones;
    out[17664 + k] = logf((float)vminus);  // log_v_minus_K
  }
}

extern "C" void kernel_launch(void* const* d_in, const int* in_sizes, int n_in,
                              void* d_out, int out_size, void* d_ws, size_t ws_size,
                              hipStream_t stream) {
  const int*   pN   = (const int*)d_in[0];
  const int*   leaf = (const int*)d_in[1];
  const float* emb  = (const float*)d_in[2];
  const float* W1   = (const float*)d_in[4];
  const float* b1   = (const float*)d_in[5];
  const float* W2   = (const float*)d_in[6];
  const float* b2   = (const float*)d_in[7];
  float* out = (float*)d_out;

  ep_fused<<<TK, NTHREADS, 0, stream>>>(pN, leaf, emb, W1, b1, W2, b2, out);
}

// Round 12
// 149.960 us; speedup vs baseline: 1.2047x; 1.0536x over previous
//
#include <hip/hip_runtime.h>
#include <stdint.h>
#include <math.h>

#define TK 256
#define TT 256
#define DD 64
#define HH 256
#define NTHREADS 1024
#define PADB 72   // bf16 row stride (144 B)

typedef short bf16x8 __attribute__((ext_vector_type(8)));
typedef float f32x4  __attribute__((ext_vector_type(4)));

struct KWs { unsigned long long packed; float ss; unsigned int arrive; unsigned int pad; };

// ---- exact JAX threefry2x32 (key=(0,42)); partitionable: ctr=(0,p), bits=x^y (R4-verified)
__device__ __forceinline__ uint32_t rotl32(uint32_t x, uint32_t d) {
  return (x << d) | (x >> (32u - d));
}
__device__ __forceinline__ uint2 threefry2x32(uint32_t x0, uint32_t x1) {
  const uint32_t ks0 = 0u, ks1 = 42u, ks2 = 0x1BD11BF0u;
  x0 += ks0; x1 += ks1;
#define TFR(r) { x0 += x1; x1 = rotl32(x1, r); x1 ^= x0; }
  TFR(13u) TFR(15u) TFR(26u) TFR(6u)
  x0 += ks1; x1 += ks2 + 1u;
  TFR(17u) TFR(29u) TFR(16u) TFR(24u)
  x0 += ks2; x1 += ks0 + 2u;
  TFR(13u) TFR(15u) TFR(26u) TFR(6u)
  x0 += ks0; x1 += ks1 + 3u;
  TFR(17u) TFR(29u) TFR(16u) TFR(24u)
  x0 += ks1; x1 += ks2 + 4u;
  TFR(13u) TFR(15u) TFR(26u) TFR(6u)
  x0 += ks2; x1 += ks0 + 5u;
#undef TFR
  return make_uint2(x0, x1);
}

__device__ __forceinline__ uint16_t f2bf(float x) {
  uint32_t u = __float_as_uint(x);
  return (uint16_t)((u + 0x7FFFu + ((u >> 16) & 1u)) >> 16);
}

__global__ __launch_bounds__(NTHREADS) void ep_fused(
    const int*   __restrict__ pN,
    const int*   __restrict__ leaf,
    const float* __restrict__ emb,
    const float* __restrict__ W1,
    const float* __restrict__ b1,
    const float* __restrict__ W2,
    const float* __restrict__ b2,
    float*       __restrict__ out,
    KWs*         __restrict__ ws)
{
  __shared__ uint16_t s_hi[TT * PADB];
  __shared__ uint16_t s_lo[TT * PADB];
  __shared__ float s_sq[TT];
  __shared__ float s_c1[DD], s_c2[DD];
  __shared__ float s_wss[16], s_wb[16];
  __shared__ int   s_wi[16], s_onesw[16], s_sel[2];
  __shared__ float s_h[HH], s_e[DD];
  __shared__ float s_lse;
  __shared__ int   s_exec;

  const int k    = blockIdx.x >> 1;      // split-k: 2 blocks per k
  const int half = blockIdx.x & 1;       // j-tile half
  const int tid  = threadIdx.x;
  const float* ek = emb + (size_t)k * (TT * DD);

  // ---- stage: fp32 global -> bf16 hi/lo split in LDS ----
  for (int idx = tid; idx < TT * DD / 4; idx += NTHREADS) {
    float4 v = ((const float4*)ek)[idx];
    int f = idx << 2;
    int r = f >> 6, c = f & 63;
    uint16_t h0 = f2bf(v.x), h1 = f2bf(v.y), h2 = f2bf(v.z), h3 = f2bf(v.w);
    float l0f = v.x - __uint_as_float((uint32_t)h0 << 16);
    float l1f = v.y - __uint_as_float((uint32_t)h1 << 16);
    float l2f = v.z - __uint_as_float((uint32_t)h2 << 16);
    float l3f = v.w - __uint_as_float((uint32_t)h3 << 16);
    uint2 hp = make_uint2((uint32_t)h0 | ((uint32_t)h1 << 16),
                          (uint32_t)h2 | ((uint32_t)h3 << 16));
    uint2 lp = make_uint2((uint32_t)f2bf(l0f) | ((uint32_t)f2bf(l1f) << 16),
                          (uint32_t)f2bf(l2f) | ((uint32_t)f2bf(l3f) << 16));
    *(uint2*)&s_hi[r * PADB + c] = hp;
    *(uint2*)&s_lo[r * PADB + c] = lp;
  }
  if (tid < TT) {
    const float* row = ek + tid * DD;
    float acc = 0.f;
#pragma unroll
    for (int c = 0; c < DD; ++c) acc = fmaf(row[c], row[c], acc);
    s_sq[tid] = acc;
  }
  __syncthreads();

  // ---- MFMA Gram + per-element tail, j restricted to this block's half ----
  const int wv = tid >> 6, l = tid & 63;
  const int lm = l & 15, lk = l >> 4;
  const int I0 = wv * 16;

  const char* hib = (const char*)s_hi;
  const char* lob = (const char*)s_lo;
  const int arow = (I0 + lm) * (PADB * 2);
  bf16x8 ah0 = *(const bf16x8*)(hib + arow + lk * 16);
  bf16x8 ah1 = *(const bf16x8*)(hib + arow + 64 + lk * 16);
  bf16x8 al0 = *(const bf16x8*)(lob + arow + lk * 16);
  bf16x8 al1 = *(const bf16x8*)(lob + arow + 64 + lk * 16);

  float sqi_r[4];
#pragma unroll
  for (int r = 0; r < 4; ++r) sqi_r[r] = s_sq[I0 + lk * 4 + r];

  float ss = 0.f, best = -3.402823466e38f;
  int bidx = 0x7fffffff;

  for (int jt = half * 8; jt < half * 8 + 8; ++jt) {
    const int J0 = jt * 16;
    const int brow = (J0 + lm) * (PADB * 2);
    bf16x8 bh0 = *(const bf16x8*)(hib + brow + lk * 16);
    bf16x8 bh1 = *(const bf16x8*)(hib + brow + 64 + lk * 16);
    bf16x8 bl0 = *(const bf16x8*)(lob + brow + lk * 16);
    bf16x8 bl1 = *(const bf16x8*)(lob + brow + 64 + lk * 16);

    f32x4 acc = {0.f, 0.f, 0.f, 0.f};
    acc = __builtin_amdgcn_mfma_f32_16x16x32_bf16(ah0, bh0, acc, 0, 0, 0);
    acc = __builtin_amdgcn_mfma_f32_16x16x32_bf16(ah0, bl0, acc, 0, 0, 0);
    acc = __builtin_amdgcn_mfma_f32_16x16x32_bf16(al0, bh0, acc, 0, 0, 0);
    acc = __builtin_amdgcn_mfma_f32_16x16x32_bf16(ah1, bh1, acc, 0, 0, 0);
    acc = __builtin_amdgcn_mfma_f32_16x16x32_bf16(ah1, bl1, acc, 0, 0, 0);
    acc = __builtin_amdgcn_mfma_f32_16x16x32_bf16(al1, bh1, acc, 0, 0, 0);

    const int j = J0 + lm;
    const float sqj = s_sq[j];
    const uint32_t pbase = ((uint32_t)k << 16) | (uint32_t)j;

#pragma unroll
    for (int r = 0; r < 4; ++r) {
      const int i = I0 + lk * 4 + r;
      float dsq = sqi_r[r] + sqj - 2.0f * acc[r];
      float lw  = -sqrtf(fmaxf(dsq, 0.f));
      if (i != j) {
        ss += __expf(lw);
        uint2 rr = threefry2x32(0u, pbase + ((uint32_t)i << 8));
        uint32_t bits = rr.x ^ rr.y;
        float f = __uint_as_float((bits >> 9) | 0x3F800000u) - 1.0f;
        float u = fmaxf(f, 1.1754943508222875e-38f);
        float g = -__logf(-__logf(u));
        float sv = lw + g;
        int fi = i * TT + j;
        if (sv > best || (sv == best && fi < bidx)) { best = sv; bidx = fi; }
      }
    }
  }

  // ---- block-level reduction ----
#pragma unroll
  for (int off = 32; off > 0; off >>= 1) {
    ss += __shfl_xor(ss, off);
    float ob = __shfl_xor(best, off);
    int   oi = __shfl_xor(bidx, off);
    if (ob > best || (ob == best && oi < bidx)) { best = ob; bidx = oi; }
  }
  if (l == 0) { s_wss[wv] = ss; s_wb[wv] = best; s_wi[wv] = bidx; }
  {
    int isone = (tid < TT) ? ((leaf[k * TT + tid] == 1) ? 1 : 0) : 0;
    unsigned long long bal = __ballot(isone);
    if (l == 0) s_onesw[wv] = __popcll(bal);
  }
  __syncthreads();

  // ---- cross-block merge via device-scope atomics; second arriver executes epilogue ----
  if (tid == 0) {
    float tot = 0.f, bb = -3.402823466e38f; int bi = 0x7fffffff;
    for (int w = 0; w < 16; ++w) {
      tot += s_wss[w];
      if (s_wb[w] > bb || (s_wb[w] == bb && s_wi[w] < bi)) { bb = s_wb[w]; bi = s_wi[w]; }
    }
    KWs* w = ws + k;
    uint32_t sb = __float_as_uint(bb);
    uint32_t mapped = (sb & 0x80000000u) ? ~sb : (sb | 0x80000000u);
    unsigned long long pk = ((unsigned long long)mapped << 32) |
                            (unsigned long long)(~(uint32_t)bi);
    atomicAdd(&w->ss, tot);
    atomicMax(&w->packed, pk);
    __threadfence();
    unsigned int old = atomicAdd(&w->arrive, 1u);
    if (old == 1u) {   // both halves merged; this block finishes k
      float tt = atomicAdd(&w->ss, 0.0f);
      unsigned long long fp = atomicMax(&w->packed, 0ull);
      int fbi = (int)(~(uint32_t)(fp & 0xFFFFFFFFull));
      s_sel[0] = fbi >> 8;
      s_sel[1] = fbi & 255;
      s_lse    = logf(tt);
      s_exec   = 1;
    } else {
      s_exec = 0;
    }
  }
  __syncthreads();
  if (!s_exec) return;

  const int i1 = s_sel[0], i2 = s_sel[1];
  if (tid < DD) {
    s_c1[tid] = ek[i1 * DD + tid];
    s_c2[tid] = ek[i2 * DD + tid];
  }
  __syncthreads();

  if (tid < HH) {
    float h0 = 0.f, h1 = 0.f;
#pragma unroll 8
    for (int c = 0; c < DD; ++c) h0 = fmaf(s_c1[c], W1[c * HH + tid], h0);
#pragma unroll 8
    for (int c = 0; c < DD; ++c) h1 = fmaf(s_c2[c], W1[(DD + c) * HH + tid], h1);
    s_h[tid] = fmaxf(h0 + h1 + b1[tid], 0.f);
  }
  __syncthreads();

  if (tid < DD) {
    float acc = 0.f;
#pragma unroll 8
    for (int hh = 0; hh < HH; ++hh) acc = fmaf(s_h[hh], W2[hh * DD + tid], acc);
    float e = acc + b2[tid];
    s_e[tid] = e;
    out[1024 + k * DD + tid] = e;
  }
  __syncthreads();

  if (tid < DD) {
    float dd1 = s_c1[tid] - s_e[tid];
    float dd2 = s_c2[tid] - s_e[tid];
    float q1 = dd1 * dd1, q2 = dd2 * dd2;
#pragma unroll
    for (int off = 32; off > 0; off >>= 1) {
      q1 += __shfl_xor(q1, off);
      q2 += __shfl_xor(q2, off);
    }
    if (tid == 0) {
      out[512 + k] = sqrtf(q1);
      out[768 + k] = sqrtf(q2);
    }
  }

  if (tid == 0) {
    float dot = 0.f;
#pragma unroll
    for (int c = 0; c < DD; ++c) dot = fmaf(s_c1[c], s_c2[c], dot);
    float dsq = s_sq[i1] + s_sq[i2] - 2.0f * dot;
    float lw  = -sqrtf(fmaxf(dsq, 0.f));
    out[0   + k] = (float)i1;
    out[256 + k] = (float)i2;
    out[17408 + k] = lw + 0.69314718055994531f - s_lse;
    int ones = 0;
    for (int w = 0; w < 16; ++w) ones += s_onesw[w];
    ones -= (leaf[k * TT + i1] == 1) ? 1 : 0;
    ones -= (leaf[k * TT + i2] == 1) ? 1 : 0;
    int vminus = pN[0] - ones;
    out[17664 + k] = logf((float)vminus);
  }
}

extern "C" void kernel_launch(void* const* d_in, const int* in_sizes, int n_in,
                              void* d_out, int out_size, void* d_ws, size_t ws_size,
                              hipStream_t stream) {
  const int*   pN   = (const int*)d_in[0];
  const int*   leaf = (const int*)d_in[1];
  const float* emb  = (const float*)d_in[2];
  const float* W1   = (const float*)d_in[4];
  const float* b1   = (const float*)d_in[5];
  const float* W2   = (const float*)d_in[6];
  const float* b2   = (const float*)d_in[7];
  float* out = (float*)d_out;
  KWs*   ws  = (KWs*)d_ws;

  hipMemsetAsync(d_ws, 0, TK * sizeof(KWs), stream);
  ep_fused<<<TK * 2, NTHREADS, 0, stream>>>(pN, leaf, emb, W1, b1, W2, b2, out, ws);
}

// Round 14
// 148.212 us; speedup vs baseline: 1.2189x; 1.0118x over previous
//
#include <hip/hip_runtime.h>
#include <stdint.h>
#include <math.h>

#define TK 256
#define TT 256
#define DD 64
#define HH 256
#define NTHREADS 1024
#define PADB 72   // bf16 row stride (144 B)

typedef short bf16x8 __attribute__((ext_vector_type(8)));
typedef float f32x4  __attribute__((ext_vector_type(4)));

// ---- exact JAX threefry2x32 (key=(0,42)); partitionable: ctr=(0,p), bits=x^y (R4-verified)
__device__ __forceinline__ uint32_t rotl32(uint32_t x, uint32_t d) {
  return (x << d) | (x >> (32u - d));
}
__device__ __forceinline__ uint2 threefry2x32(uint32_t x0, uint32_t x1) {
  const uint32_t ks0 = 0u, ks1 = 42u, ks2 = 0x1BD11BF0u;
  x0 += ks0; x1 += ks1;
#define TFR(r) { x0 += x1; x1 = rotl32(x1, r); x1 ^= x0; }
  TFR(13u) TFR(15u) TFR(26u) TFR(6u)
  x0 += ks1; x1 += ks2 + 1u;
  TFR(17u) TFR(29u) TFR(16u) TFR(24u)
  x0 += ks2; x1 += ks0 + 2u;
  TFR(13u) TFR(15u) TFR(26u) TFR(6u)
  x0 += ks0; x1 += ks1 + 3u;
  TFR(17u) TFR(29u) TFR(16u) TFR(24u)
  x0 += ks1; x1 += ks2 + 4u;
  TFR(13u) TFR(15u) TFR(26u) TFR(6u)
  x0 += ks2; x1 += ks0 + 5u;
#undef TFR
  return make_uint2(x0, x1);
}

__device__ __forceinline__ uint16_t f2bf(float x) {
  uint32_t u = __float_as_uint(x);
  return (uint16_t)((u + 0x7FFFu + ((u >> 16) & 1u)) >> 16);
}

__global__ __launch_bounds__(NTHREADS, 4) void ep_fused(
    const int*   __restrict__ pN,
    const int*   __restrict__ leaf,
    const float* __restrict__ emb,
    const float* __restrict__ W1,
    const float* __restrict__ b1,
    const float* __restrict__ W2,
    const float* __restrict__ b2,
    float*       __restrict__ out)
{
  __shared__ uint16_t s_hi[TT * PADB];
  __shared__ uint16_t s_lo[TT * PADB];
  __shared__ float s_sq[TT];
  __shared__ float s_c1[DD], s_c2[DD];
  __shared__ float s_wss[16], s_wb[16];
  __shared__ int   s_wi[16], s_onesw[16], s_sel[2];
  __shared__ float s_h[HH], s_e[DD];
  __shared__ float s_lse;

  const int k   = blockIdx.x;
  const int tid = threadIdx.x;
  const float* ek = emb + (size_t)k * (TT * DD);

  // ---- stage: fp32 global -> bf16 hi/lo split in LDS ----
  for (int idx = tid; idx < TT * DD / 4; idx += NTHREADS) {
    float4 v = ((const float4*)ek)[idx];
    int f = idx << 2;
    int r = f >> 6, c = f & 63;
    uint16_t h0 = f2bf(v.x), h1 = f2bf(v.y), h2 = f2bf(v.z), h3 = f2bf(v.w);
    float l0f = v.x - __uint_as_float((uint32_t)h0 << 16);
    float l1f = v.y - __uint_as_float((uint32_t)h1 << 16);
    float l2f = v.z - __uint_as_float((uint32_t)h2 << 16);
    float l3f = v.w - __uint_as_float((uint32_t)h3 << 16);
    uint2 hp = make_uint2((uint32_t)h0 | ((uint32_t)h1 << 16),
                          (uint32_t)h2 | ((uint32_t)h3 << 16));
    uint2 lp = make_uint2((uint32_t)f2bf(l0f) | ((uint32_t)f2bf(l1f) << 16),
                          (uint32_t)f2bf(l2f) | ((uint32_t)f2bf(l3f) << 16));
    *(uint2*)&s_hi[r * PADB + c] = hp;
    *(uint2*)&s_lo[r * PADB + c] = lp;
  }
  if (tid < TT) {
    const float* row = ek + tid * DD;
    float acc = 0.f;
#pragma unroll
    for (int c = 0; c < DD; ++c) acc = fmaf(row[c], row[c], acc);
    s_sq[tid] = acc;
  }
  __syncthreads();

  const int wv = tid >> 6, l = tid & 63;
  const int lm = l & 15, lk = l >> 4;
  const int I0 = wv * 16;

  const char* hib = (const char*)s_hi;
  const char* lob = (const char*)s_lo;
  const int arow = (I0 + lm) * (PADB * 2);
  bf16x8 ah0 = *(const bf16x8*)(hib + arow + lk * 16);
  bf16x8 ah1 = *(const bf16x8*)(hib + arow + 64 + lk * 16);
  bf16x8 al0 = *(const bf16x8*)(lob + arow + lk * 16);
  bf16x8 al1 = *(const bf16x8*)(lob + arow + 64 + lk * 16);

  float sqi_r[4];
#pragma unroll
  for (int r = 0; r < 4; ++r) sqi_r[r] = s_sq[I0 + lk * 4 + r];

  float ss = 0.f, best = -3.402823466e38f;
  int bidx = 0x7fffffff;

  // ---- two half-passes: {phase1: MFMA->acc[8] in regs} barrier {phase2: pure-VALU tail}
  for (int hf = 0; hf < 2; ++hf) {
    f32x4 acc[8];

#pragma unroll
    for (int t = 0; t < 8; ++t) {
      const int J0 = (hf * 8 + t) * 16;
      const int brow = (J0 + lm) * (PADB * 2);
      bf16x8 bh0 = *(const bf16x8*)(hib + brow + lk * 16);
      bf16x8 bh1 = *(const bf16x8*)(hib + brow + 64 + lk * 16);
      bf16x8 bl0 = *(const bf16x8*)(lob + brow + lk * 16);
      bf16x8 bl1 = *(const bf16x8*)(lob + brow + 64 + lk * 16);
      f32x4 a4 = {0.f, 0.f, 0.f, 0.f};
      a4 = __builtin_amdgcn_mfma_f32_16x16x32_bf16(ah0, bh0, a4, 0, 0, 0);
      a4 = __builtin_amdgcn_mfma_f32_16x16x32_bf16(ah0, bl0, a4, 0, 0, 0);
      a4 = __builtin_amdgcn_mfma_f32_16x16x32_bf16(al0, bh0, a4, 0, 0, 0);
      a4 = __builtin_amdgcn_mfma_f32_16x16x32_bf16(ah1, bh1, a4, 0, 0, 0);
      a4 = __builtin_amdgcn_mfma_f32_16x16x32_bf16(ah1, bl1, a4, 0, 0, 0);
      a4 = __builtin_amdgcn_mfma_f32_16x16x32_bf16(al1, bh1, a4, 0, 0, 0);
      acc[t] = a4;
    }

    __builtin_amdgcn_sched_barrier(0);   // keep tail OUT of the MFMA/LDS loop

#pragma unroll
    for (int t = 0; t < 8; ++t) {
      const int jt = hf * 8 + t;
      const int j = jt * 16 + lm;
      const float sqj = s_sq[j];
      const uint32_t pbase = ((uint32_t)k << 16) | (uint32_t)j;
#pragma unroll
      for (int r = 0; r < 4; ++r) {
        const int i = I0 + lk * 4 + r;
        float dsq = sqi_r[r] + sqj - 2.0f * acc[t][r];
        float lw  = -sqrtf(fmaxf(dsq, 0.f));
        if (i != j) {
          ss += __expf(lw);
          uint2 rr = threefry2x32(0u, pbase + ((uint32_t)i << 8));
          uint32_t bits = rr.x ^ rr.y;
          float f = __uint_as_float((bits >> 9) | 0x3F800000u) - 1.0f;
          float u = fmaxf(f, 1.1754943508222875e-38f);
          float g = -__logf(-__logf(u));
          float sv = lw + g;
          int fi = i * TT + j;
          if (sv > best || (sv == best && fi < bidx)) { best = sv; bidx = fi; }
        }
      }
    }
  }

  // ---- block reduction (R11 path) ----
#pragma unroll
  for (int off = 32; off > 0; off >>= 1) {
    ss += __shfl_xor(ss, off);
    float ob = __shfl_xor(best, off);
    int   oi = __shfl_xor(bidx, off);
    if (ob > best || (ob == best && oi < bidx)) { best = ob; bidx = oi; }
  }
  if (l == 0) { s_wss[wv] = ss; s_wb[wv] = best; s_wi[wv] = bidx; }
  {
    int isone = (tid < TT) ? ((leaf[k * TT + tid] == 1) ? 1 : 0) : 0;
    unsigned long long bal = __ballot(isone);
    if (l == 0) s_onesw[wv] = __popcll(bal);
  }
  __syncthreads();

  if (tid == 0) {
    float tot = 0.f, bb = -3.402823466e38f; int bi = 0x7fffffff;
    for (int w = 0; w < 16; ++w) {
      tot += s_wss[w];
      if (s_wb[w] > bb || (s_wb[w] == bb && s_wi[w] < bi)) { bb = s_wb[w]; bi = s_wi[w]; }
    }
    s_sel[0] = bi >> 8;
    s_sel[1] = bi & 255;
    s_lse    = logf(tot);
  }
  __syncthreads();

  const int i1 = s_sel[0], i2 = s_sel[1];
  if (tid < DD) {
    s_c1[tid] = ek[i1 * DD + tid];
    s_c2[tid] = ek[i2 * DD + tid];
  }
  __syncthreads();

  if (tid < HH) {
    float h0 = 0.f, h1 = 0.f;
#pragma unroll 8
    for (int c = 0; c < DD; ++c) h0 = fmaf(s_c1[c], W1[c * HH + tid], h0);
#pragma unroll 8
    for (int c = 0; c < DD; ++c) h1 = fmaf(s_c2[c], W1[(DD + c) * HH + tid], h1);
    s_h[tid] = fmaxf(h0 + h1 + b1[tid], 0.f);
  }
  __syncthreads();

  if (tid < DD) {
    float acc = 0.f;
#pragma unroll 8
    for (int hh = 0; hh < HH; ++hh) acc = fmaf(s_h[hh], W2[hh * DD + tid], acc);
    float e = acc + b2[tid];
    s_e[tid] = e;
    out[1024 + k * DD + tid] = e;
  }
  __syncthreads();

  if (tid < DD) {
    float dd1 = s_c1[tid] - s_e[tid];
    float dd2 = s_c2[tid] - s_e[tid];
    float q1 = dd1 * dd1, q2 = dd2 * dd2;
#pragma unroll
    for (int off = 32; off > 0; off >>= 1) {
      q1 += __shfl_xor(q1, off);
      q2 += __shfl_xor(q2, off);
    }
    if (tid == 0) {
      out[512 + k] = sqrtf(q1);
      out[768 + k] = sqrtf(q2);
    }
  }

  if (tid == 0) {
    float dot = 0.f;
#pragma unroll
    for (int c = 0; c < DD; ++c) dot = fmaf(s_c1[c], s_c2[c], dot);
    float dsq = s_sq[i1] + s_sq[i2] - 2.0f * dot;
    float lw  = -sqrtf(fmaxf(dsq, 0.f));
    out[0   + k] = (float)i1;
    out[256 + k] = (float)i2;
    out[17408 + k] = lw + 0.69314718055994531f - s_lse;
    int ones = 0;
    for (int w = 0; w < 16; ++w) ones += s_onesw[w];
    ones -= (leaf[k * TT + i1] == 1) ? 1 : 0;
    ones -= (leaf[k * TT + i2] == 1) ? 1 : 0;
    int vminus = pN[0] - ones;
    out[17664 + k] = logf((float)vminus);
  }
}

extern "C" void kernel_launch(void* const* d_in, const int* in_sizes, int n_in,
                              void* d_out, int out_size, void* d_ws, size_t ws_size,
                              hipStream_t stream) {
  const int*   pN   = (const int*)d_in[0];
  const int*   leaf = (const int*)d_in[1];
  const float* emb  = (const float*)d_in[2];
  const float* W1   = (const float*)d_in[4];
  const float* b1   = (const float*)d_in[5];
  const float* W2   = (const float*)d_in[6];
  const float* b2   = (const float*)d_in[7];
  float* out = (float*)d_out;

  ep_fused<<<TK, NTHREADS, 0, stream>>>(pN, leaf, emb, W1, b1, W2, b2, out);
}

// Round 16
// 146.103 us; speedup vs baseline: 1.2365x; 1.0144x over previous
//
#include <hip/hip_runtime.h>
#include <stdint.h>
#include <math.h>

#define TK 256
#define TT 256
#define DD 64
#define HH 256
#define NTHREADS 1024
#define PADB 72   // bf16 row stride (144 B)

typedef short bf16x8 __attribute__((ext_vector_type(8)));
typedef float f32x4  __attribute__((ext_vector_type(4)));

struct KWs { unsigned long long packed; float ss; unsigned int arrive; unsigned int pad; };

// ---- exact JAX threefry2x32 (key=(0,42)); partitionable: ctr=(0,p), bits=x^y (R4-verified)
__device__ __forceinline__ uint32_t rotl32(uint32_t x, uint32_t d) {
  return (x << d) | (x >> (32u - d));
}
__device__ __forceinline__ uint2 threefry2x32(uint32_t x0, uint32_t x1) {
  const uint32_t ks0 = 0u, ks1 = 42u, ks2 = 0x1BD11BF0u;
  x0 += ks0; x1 += ks1;
#define TFR(r) { x0 += x1; x1 = rotl32(x1, r); x1 ^= x0; }
  TFR(13u) TFR(15u) TFR(26u) TFR(6u)
  x0 += ks1; x1 += ks2 + 1u;
  TFR(17u) TFR(29u) TFR(16u) TFR(24u)
  x0 += ks2; x1 += ks0 + 2u;
  TFR(13u) TFR(15u) TFR(26u) TFR(6u)
  x0 += ks0; x1 += ks1 + 3u;
  TFR(17u) TFR(29u) TFR(16u) TFR(24u)
  x0 += ks1; x1 += ks2 + 4u;
  TFR(13u) TFR(15u) TFR(26u) TFR(6u)
  x0 += ks2; x1 += ks0 + 5u;
#undef TFR
  return make_uint2(x0, x1);
}

__device__ __forceinline__ uint16_t f2bf(float x) {
  uint32_t u = __float_as_uint(x);
  return (uint16_t)((u + 0x7FFFu + ((u >> 16) & 1u)) >> 16);
}

__global__ __launch_bounds__(NTHREADS, 8) void ep_fused(
    const int*   __restrict__ pN,
    const int*   __restrict__ leaf,
    const float* __restrict__ emb,
    const float* __restrict__ W1,
    const float* __restrict__ b1,
    const float* __restrict__ W2,
    const float* __restrict__ b2,
    float*       __restrict__ out,
    KWs*         __restrict__ ws)
{
  __shared__ uint16_t s_hi[TT * PADB];
  __shared__ uint16_t s_lo[TT * PADB];
  __shared__ float s_sq[TT];
  __shared__ float s_c1[DD], s_c2[DD];
  __shared__ float s_wss[16], s_wb[16];
  __shared__ int   s_wi[16], s_onesw[16], s_sel[2];
  __shared__ float s_h[HH], s_e[DD];
  __shared__ float s_lse;
  __shared__ int   s_exec;

  const int k    = blockIdx.x >> 1;      // split-k: 2 blocks per k
  const int half = blockIdx.x & 1;       // j-tile half
  const int tid  = threadIdx.x;
  const float* ek = emb + (size_t)k * (TT * DD);

  // ---- stage: fp32 global -> bf16 hi/lo split in LDS ----
  for (int idx = tid; idx < TT * DD / 4; idx += NTHREADS) {
    float4 v = ((const float4*)ek)[idx];
    int f = idx << 2;
    int r = f >> 6, c = f & 63;
    uint16_t h0 = f2bf(v.x), h1 = f2bf(v.y), h2 = f2bf(v.z), h3 = f2bf(v.w);
    float l0f = v.x - __uint_as_float((uint32_t)h0 << 16);
    float l1f = v.y - __uint_as_float((uint32_t)h1 << 16);
    float l2f = v.z - __uint_as_float((uint32_t)h2 << 16);
    float l3f = v.w - __uint_as_float((uint32_t)h3 << 16);
    uint2 hp = make_uint2((uint32_t)h0 | ((uint32_t)h1 << 16),
                          (uint32_t)h2 | ((uint32_t)h3 << 16));
    uint2 lp = make_uint2((uint32_t)f2bf(l0f) | ((uint32_t)f2bf(l1f) << 16),
                          (uint32_t)f2bf(l2f) | ((uint32_t)f2bf(l3f) << 16));
    *(uint2*)&s_hi[r * PADB + c] = hp;
    *(uint2*)&s_lo[r * PADB + c] = lp;
  }
  if (tid < TT) {
    const float* row = ek + tid * DD;
    float acc = 0.f;
#pragma unroll
    for (int c = 0; c < DD; ++c) acc = fmaf(row[c], row[c], acc);
    s_sq[tid] = acc;
  }
  __syncthreads();

  const int wv = tid >> 6, l = tid & 63;
  const int lm = l & 15, lk = l >> 4;
  const int I0 = wv * 16;

  const char* hib = (const char*)s_hi;
  const char* lob = (const char*)s_lo;
  const int arow = (I0 + lm) * (PADB * 2);
  bf16x8 ah0 = *(const bf16x8*)(hib + arow + lk * 16);
  bf16x8 ah1 = *(const bf16x8*)(hib + arow + 64 + lk * 16);
  bf16x8 al0 = *(const bf16x8*)(lob + arow + lk * 16);
  bf16x8 al1 = *(const bf16x8*)(lob + arow + 64 + lk * 16);

  float sqi_r[4];
#pragma unroll
  for (int r = 0; r < 4; ++r) sqi_r[r] = s_sq[I0 + lk * 4 + r];

  float ss = 0.f, best = -3.402823466e38f;
  int bidx = 0x7fffffff;

  // ---- this block's 8 j-tiles, in 2 chunks of 4: {MFMA->acc[4]} SB {pure-VALU tail}
  for (int ch = 0; ch < 2; ++ch) {
    f32x4 acc[4];

#pragma unroll
    for (int t = 0; t < 4; ++t) {
      const int J0 = (half * 8 + ch * 4 + t) * 16;
      const int brow = (J0 + lm) * (PADB * 2);
      bf16x8 bh0 = *(const bf16x8*)(hib + brow + lk * 16);
      bf16x8 bh1 = *(const bf16x8*)(hib + brow + 64 + lk * 16);
      bf16x8 bl0 = *(const bf16x8*)(lob + brow + lk * 16);
      bf16x8 bl1 = *(const bf16x8*)(lob + brow + 64 + lk * 16);
      f32x4 a4 = {0.f, 0.f, 0.f, 0.f};
      a4 = __builtin_amdgcn_mfma_f32_16x16x32_bf16(ah0, bh0, a4, 0, 0, 0);
      a4 = __builtin_amdgcn_mfma_f32_16x16x32_bf16(ah0, bl0, a4, 0, 0, 0);
      a4 = __builtin_amdgcn_mfma_f32_16x16x32_bf16(al0, bh0, a4, 0, 0, 0);
      a4 = __builtin_amdgcn_mfma_f32_16x16x32_bf16(ah1, bh1, a4, 0, 0, 0);
      a4 = __builtin_amdgcn_mfma_f32_16x16x32_bf16(ah1, bl1, a4, 0, 0, 0);
      a4 = __builtin_amdgcn_mfma_f32_16x16x32_bf16(al1, bh1, a4, 0, 0, 0);
      acc[t] = a4;
    }

    __builtin_amdgcn_sched_barrier(0);   // keep tail OUT of the MFMA/LDS region

#pragma unroll
    for (int t = 0; t < 4; ++t) {
      const int jt = half * 8 + ch * 4 + t;
      const int j = jt * 16 + lm;
      const float sqj = s_sq[j];
      const uint32_t pbase = ((uint32_t)k << 16) | (uint32_t)j;
#pragma unroll
      for (int r = 0; r < 4; ++r) {
        const int i = I0 + lk * 4 + r;
        float dsq = sqi_r[r] + sqj - 2.0f * acc[t][r];
        float lw  = -__builtin_amdgcn_sqrtf(fmaxf(dsq, 0.f));
        if (i != j) {
          ss += __expf(lw);
          uint2 rr = threefry2x32(0u, pbase + ((uint32_t)i << 8));
          uint32_t bits = rr.x ^ rr.y;
          float f = __uint_as_float((bits >> 9) | 0x3F800000u) - 1.0f;
          float u = fmaxf(f, 1.1754943508222875e-38f);
          float g = -__logf(-__logf(u));
          float sv = lw + g;
          int fi = i * TT + j;
          if (sv > best || (sv == best && fi < bidx)) { best = sv; bidx = fi; }
        }
      }
    }
  }

  // ---- block reduction ----
#pragma unroll
  for (int off = 32; off > 0; off >>= 1) {
    ss += __shfl_xor(ss, off);
    float ob = __shfl_xor(best, off);
    int   oi = __shfl_xor(bidx, off);
    if (ob > best || (ob == best && oi < bidx)) { best = ob; bidx = oi; }
  }
  if (l == 0) { s_wss[wv] = ss; s_wb[wv] = best; s_wi[wv] = bidx; }
  {
    int isone = (tid < TT) ? ((leaf[k * TT + tid] == 1) ? 1 : 0) : 0;
    unsigned long long bal = __ballot(isone);
    if (l == 0) s_onesw[wv] = __popcll(bal);
  }
  __syncthreads();

  // ---- cross-block merge via device-scope atomics; second arriver runs epilogue ----
  if (tid == 0) {
    float tot = 0.f, bb = -3.402823466e38f; int bi = 0x7fffffff;
    for (int w = 0; w < 16; ++w) {
      tot += s_wss[w];
      if (s_wb[w] > bb || (s_wb[w] == bb && s_wi[w] < bi)) { bb = s_wb[w]; bi = s_wi[w]; }
    }
    KWs* w = ws + k;
    uint32_t sb = __float_as_uint(bb);
    uint32_t mapped = (sb & 0x80000000u) ? ~sb : (sb | 0x80000000u);
    unsigned long long pk = ((unsigned long long)mapped << 32) |
                            (unsigned long long)(~(uint32_t)bi);
    atomicAdd(&w->ss, tot);
    atomicMax(&w->packed, pk);
    __threadfence();
    unsigned int old = atomicAdd(&w->arrive, 1u);
    if (old == 1u) {
      float tt = atomicAdd(&w->ss, 0.0f);
      unsigned long long fp = atomicMax(&w->packed, 0ull);
      int fbi = (int)(~(uint32_t)(fp & 0xFFFFFFFFull));
      s_sel[0] = fbi >> 8;
      s_sel[1] = fbi & 255;
      s_lse    = logf(tt);
      s_exec   = 1;
    } else {
      s_exec = 0;
    }
  }
  __syncthreads();
  if (!s_exec) return;

  const int i1 = s_sel[0], i2 = s_sel[1];
  if (tid < DD) {
    s_c1[tid] = ek[i1 * DD + tid];
    s_c2[tid] = ek[i2 * DD + tid];
  }
  __syncthreads();

  if (tid < HH) {
    float h0 = 0.f, h1 = 0.f;
#pragma unroll 8
    for (int c = 0; c < DD; ++c) h0 = fmaf(s_c1[c], W1[c * HH + tid], h0);
#pragma unroll 8
    for (int c = 0; c < DD; ++c) h1 = fmaf(s_c2[c], W1[(DD + c) * HH + tid], h1);
    s_h[tid] = fmaxf(h0 + h1 + b1[tid], 0.f);
  }
  __syncthreads();

  if (tid < DD) {
    float acc = 0.f;
#pragma unroll 8
    for (int hh = 0; hh < HH; ++hh) acc = fmaf(s_h[hh], W2[hh * DD + tid], acc);
    float e = acc + b2[tid];
    s_e[tid] = e;
    out[1024 + k * DD + tid] = e;
  }
  __syncthreads();

  if (tid < DD) {
    float dd1 = s_c1[tid] - s_e[tid];
    float dd2 = s_c2[tid] - s_e[tid];
    float q1 = dd1 * dd1, q2 = dd2 * dd2;
#pragma unroll
    for (int off = 32; off > 0; off >>= 1) {
      q1 += __shfl_xor(q1, off);
      q2 += __shfl_xor(q2, off);
    }
    if (tid == 0) {
      out[512 + k] = sqrtf(q1);
      out[768 + k] = sqrtf(q2);
    }
  }

  if (tid == 0) {
    float dot = 0.f;
#pragma unroll
    for (int c = 0; c < DD; ++c) dot = fmaf(s_c1[c], s_c2[c], dot);
    float dsq = s_sq[i1] + s_sq[i2] - 2.0f * dot;
    float lw  = -sqrtf(fmaxf(dsq, 0.f));
    out[0   + k] = (float)i1;
    out[256 + k] = (float)i2;
    out[17408 + k] = lw + 0.69314718055994531f - s_lse;
    int ones = 0;
    for (int w = 0; w < 16; ++w) ones += s_onesw[w];
    ones -= (leaf[k * TT + i1] == 1) ? 1 : 0;
    ones -= (leaf[k * TT + i2] == 1) ? 1 : 0;
    int vminus = pN[0] - ones;
    out[17664 + k] = logf((float)vminus);
  }
}

extern "C" void kernel_launch(void* const* d_in, const int* in_sizes, int n_in,
                              void* d_out, int out_size, void* d_ws, size_t ws_size,
                              hipStream_t stream) {
  const int*   pN   = (const int*)d_in[0];
  const int*   leaf = (const int*)d_in[1];
  const float* emb  = (const float*)d_in[2];
  const float* W1   = (const float*)d_in[4];
  const float* b1   = (const float*)d_in[5];
  const float* W2   = (const float*)d_in[6];
  const float* b2   = (const float*)d_in[7];
  float* out = (float*)d_out;
  KWs*   ws  = (KWs*)d_ws;

  (void)hipMemsetAsync(d_ws, 0, TK * sizeof(KWs), stream);
  ep_fused<<<TK * 2, NTHREADS, 0, stream>>>(pN, leaf, emb, W1, b1, W2, b2, out, ws);
}

// Round 17
// 143.644 us; speedup vs baseline: 1.2577x; 1.0171x over previous
//
#include <hip/hip_runtime.h>
#include <stdint.h>
#include <math.h>

#define TK 256
#define TT 256
#define DD 64
#define HH 256
#define NTHREADS 1024
#define PADB 72   // bf16 row stride (144 B)

typedef short bf16x8 __attribute__((ext_vector_type(8)));
typedef float f32x4  __attribute__((ext_vector_type(4)));

struct KWs { unsigned long long packed; float ss; unsigned int arrive; unsigned int pad; };

// ---- exact JAX threefry2x32 (key=(0,42)); partitionable: ctr=(0,p), bits=x^y (R4-verified)
// rotl(x,d) == rotr(x,32-d) == v_alignbit_b32(x,x,32-d): forced single-instruction rotate.
__device__ __forceinline__ uint2 threefry2x32(uint32_t x0, uint32_t x1) {
  const uint32_t ks0 = 0u, ks1 = 42u, ks2 = 0x1BD11BF0u;
  x0 += ks0; x1 += ks1;
#define TFR(r) { x0 += x1; x1 = __builtin_amdgcn_alignbit(x1, x1, 32u - (r)); x1 ^= x0; }
  TFR(13u) TFR(15u) TFR(26u) TFR(6u)
  x0 += ks1; x1 += ks2 + 1u;
  TFR(17u) TFR(29u) TFR(16u) TFR(24u)
  x0 += ks2; x1 += ks0 + 2u;
  TFR(13u) TFR(15u) TFR(26u) TFR(6u)
  x0 += ks0; x1 += ks1 + 3u;
  TFR(17u) TFR(29u) TFR(16u) TFR(24u)
  x0 += ks1; x1 += ks2 + 4u;
  TFR(13u) TFR(15u) TFR(26u) TFR(6u)
  x0 += ks2; x1 += ks0 + 5u;
#undef TFR
  return make_uint2(x0, x1);
}

__device__ __forceinline__ uint16_t f2bf(float x) {
  uint32_t u = __float_as_uint(x);
  return (uint16_t)((u + 0x7FFFu + ((u >> 16) & 1u)) >> 16);
}

__global__ __launch_bounds__(NTHREADS, 8) void ep_fused(
    const int*   __restrict__ pN,
    const int*   __restrict__ leaf,
    const float* __restrict__ emb,
    const float* __restrict__ W1,
    const float* __restrict__ b1,
    const float* __restrict__ W2,
    const float* __restrict__ b2,
    float*       __restrict__ out,
    KWs*         __restrict__ ws)
{
  __shared__ uint16_t s_hi[TT * PADB];
  __shared__ uint16_t s_lo[TT * PADB];
  __shared__ float s_sq[TT];
  __shared__ float s_c1[DD], s_c2[DD];
  __shared__ float s_wss[16], s_wb[16];
  __shared__ int   s_wi[16], s_onesw[16], s_sel[2];
  __shared__ float s_h[HH], s_e[DD];
  __shared__ float s_lse;
  __shared__ int   s_exec;

  const int k    = blockIdx.x >> 1;      // split-k: 2 blocks per k
  const int half = blockIdx.x & 1;       // j-tile half
  const int tid  = threadIdx.x;
  const float* ek = emb + (size_t)k * (TT * DD);

  // ---- stage: fp32 global -> bf16 hi/lo split in LDS ----
  for (int idx = tid; idx < TT * DD / 4; idx += NTHREADS) {
    float4 v = ((const float4*)ek)[idx];
    int f = idx << 2;
    int r = f >> 6, c = f & 63;
    uint16_t h0 = f2bf(v.x), h1 = f2bf(v.y), h2 = f2bf(v.z), h3 = f2bf(v.w);
    float l0f = v.x - __uint_as_float((uint32_t)h0 << 16);
    float l1f = v.y - __uint_as_float((uint32_t)h1 << 16);
    float l2f = v.z - __uint_as_float((uint32_t)h2 << 16);
    float l3f = v.w - __uint_as_float((uint32_t)h3 << 16);
    uint2 hp = make_uint2((uint32_t)h0 | ((uint32_t)h1 << 16),
                          (uint32_t)h2 | ((uint32_t)h3 << 16));
    uint2 lp = make_uint2((uint32_t)f2bf(l0f) | ((uint32_t)f2bf(l1f) << 16),
                          (uint32_t)f2bf(l2f) | ((uint32_t)f2bf(l3f) << 16));
    *(uint2*)&s_hi[r * PADB + c] = hp;
    *(uint2*)&s_lo[r * PADB + c] = lp;
  }
  if (tid < TT) {
    const float* row = ek + tid * DD;
    float acc = 0.f;
#pragma unroll
    for (int c = 0; c < DD; ++c) acc = fmaf(row[c], row[c], acc);
    s_sq[tid] = acc;
  }
  __syncthreads();

  const int wv = tid >> 6, l = tid & 63;
  const int lm = l & 15, lk = l >> 4;
  const int I0 = wv * 16;

  const char* hib = (const char*)s_hi;
  const char* lob = (const char*)s_lo;
  const int arow = (I0 + lm) * (PADB * 2);
  bf16x8 ah0 = *(const bf16x8*)(hib + arow + lk * 16);
  bf16x8 ah1 = *(const bf16x8*)(hib + arow + 64 + lk * 16);
  bf16x8 al0 = *(const bf16x8*)(lob + arow + lk * 16);
  bf16x8 al1 = *(const bf16x8*)(lob + arow + 64 + lk * 16);

  float sqi_r[4];
  uint32_t pki_r[4];                      // (k<<16) | (i<<8), hoisted
#pragma unroll
  for (int r = 0; r < 4; ++r) {
    const int i = I0 + lk * 4 + r;
    sqi_r[r] = s_sq[i];
    pki_r[r] = ((uint32_t)k << 16) | ((uint32_t)i << 8);
  }

  float ss = 0.f, best = -3.402823466e38f;
  int bidx = 0x7fffffff;

  // ---- 8 j-tiles in 2 chunks of 4: {MFMA->acc[4]} SB {pure-VALU tail}
  for (int ch = 0; ch < 2; ++ch) {
    f32x4 acc[4];

#pragma unroll
    for (int t = 0; t < 4; ++t) {
      const int J0 = (half * 8 + ch * 4 + t) * 16;
      const int brow = (J0 + lm) * (PADB * 2);
      bf16x8 bh0 = *(const bf16x8*)(hib + brow + lk * 16);
      bf16x8 bh1 = *(const bf16x8*)(hib + brow + 64 + lk * 16);
      bf16x8 bl0 = *(const bf16x8*)(lob + brow + lk * 16);
      bf16x8 bl1 = *(const bf16x8*)(lob + brow + 64 + lk * 16);
      f32x4 a4 = {0.f, 0.f, 0.f, 0.f};
      a4 = __builtin_amdgcn_mfma_f32_16x16x32_bf16(ah0, bh0, a4, 0, 0, 0);
      a4 = __builtin_amdgcn_mfma_f32_16x16x32_bf16(ah0, bl0, a4, 0, 0, 0);
      a4 = __builtin_amdgcn_mfma_f32_16x16x32_bf16(al0, bh0, a4, 0, 0, 0);
      a4 = __builtin_amdgcn_mfma_f32_16x16x32_bf16(ah1, bh1, a4, 0, 0, 0);
      a4 = __builtin_amdgcn_mfma_f32_16x16x32_bf16(ah1, bl1, a4, 0, 0, 0);
      a4 = __builtin_amdgcn_mfma_f32_16x16x32_bf16(al1, bh1, a4, 0, 0, 0);
      acc[t] = a4;
    }

    __builtin_amdgcn_sched_barrier(0);   // keep tail OUT of the MFMA/LDS region

#pragma unroll
    for (int t = 0; t < 4; ++t) {
      const int jt = half * 8 + ch * 4 + t;
      const int j = jt * 16 + lm;
      const float sqj = s_sq[j];
#pragma unroll
      for (int r = 0; r < 4; ++r) {
        const int i = I0 + lk * 4 + r;
        float dsq = sqi_r[r] + sqj - 2.0f * acc[t][r];
        float lw  = -__builtin_amdgcn_sqrtf(fmaxf(dsq, 0.f));
        // branchless diagonal: -inf kills both the LSE term and the argmax candidate
        lw = (i == j) ? -__builtin_inff() : lw;
        ss += __expf(lw);
        uint2 rr = threefry2x32(0u, pki_r[r] + (uint32_t)j);
        uint32_t bits = rr.x ^ rr.y;
        float f = __uint_as_float((bits >> 9) | 0x3F800000u) - 1.0f;
        float u = fmaxf(f, 1.1754943508222875e-38f);
        // log2-domain gumbel: g = -ln2*log2(-log2(u)) - ln2*log2(ln2)
        float l2  = __builtin_amdgcn_logf(u);          // v_log_f32 = log2
        float l22 = __builtin_amdgcn_logf(-l2);        // negation folds to src modifier
        float g   = fmaf(-0.69314718055994531f, l22, 0.36651292058166435f);
        float sv = lw + g;
        int fi = i * TT + j;
        if (sv > best || (sv == best && fi < bidx)) { best = sv; bidx = fi; }
      }
    }
  }

  // ---- block reduction ----
#pragma unroll
  for (int off = 32; off > 0; off >>= 1) {
    ss += __shfl_xor(ss, off);
    float ob = __shfl_xor(best, off);
    int   oi = __shfl_xor(bidx, off);
    if (ob > best || (ob == best && oi < bidx)) { best = ob; bidx = oi; }
  }
  if (l == 0) { s_wss[wv] = ss; s_wb[wv] = best; s_wi[wv] = bidx; }
  {
    int isone = (tid < TT) ? ((leaf[k * TT + tid] == 1) ? 1 : 0) : 0;
    unsigned long long bal = __ballot(isone);
    if (l == 0) s_onesw[wv] = __popcll(bal);
  }
  __syncthreads();

  // ---- cross-block merge via device-scope atomics; second arriver runs epilogue ----
  if (tid == 0) {
    float tot = 0.f, bb = -3.402823466e38f; int bi = 0x7fffffff;
    for (int w = 0; w < 16; ++w) {
      tot += s_wss[w];
      if (s_wb[w] > bb || (s_wb[w] == bb && s_wi[w] < bi)) { bb = s_wb[w]; bi = s_wi[w]; }
    }
    KWs* w = ws + k;
    uint32_t sb = __float_as_uint(bb);
    uint32_t mapped = (sb & 0x80000000u) ? ~sb : (sb | 0x80000000u);
    unsigned long long pk = ((unsigned long long)mapped << 32) |
                            (unsigned long long)(~(uint32_t)bi);
    atomicAdd(&w->ss, tot);
    atomicMax(&w->packed, pk);
    __threadfence();
    unsigned int old = atomicAdd(&w->arrive, 1u);
    if (old == 1u) {
      float tt = atomicAdd(&w->ss, 0.0f);
      unsigned long long fp = atomicMax(&w->packed, 0ull);
      int fbi = (int)(~(uint32_t)(fp & 0xFFFFFFFFull));
      s_sel[0] = fbi >> 8;
      s_sel[1] = fbi & 255;
      s_lse    = logf(tt);
      s_exec   = 1;
    } else {
      s_exec = 0;
    }
  }
  __syncthreads();
  if (!s_exec) return;

  const int i1 = s_sel[0], i2 = s_sel[1];
  if (tid < DD) {
    s_c1[tid] = ek[i1 * DD + tid];
    s_c2[tid] = ek[i2 * DD + tid];
  }
  __syncthreads();

  if (tid < HH) {
    float h0 = 0.f, h1 = 0.f;
#pragma unroll 8
    for (int c = 0; c < DD; ++c) h0 = fmaf(s_c1[c], W1[c * HH + tid], h0);
#pragma unroll 8
    for (int c = 0; c < DD; ++c) h1 = fmaf(s_c2[c], W1[(DD + c) * HH + tid], h1);
    s_h[tid] = fmaxf(h0 + h1 + b1[tid], 0.f);
  }
  __syncthreads();

  if (tid < DD) {
    float acc = 0.f;
#pragma unroll 8
    for (int hh = 0; hh < HH; ++hh) acc = fmaf(s_h[hh], W2[hh * DD + tid], acc);
    float e = acc + b2[tid];
    s_e[tid] = e;
    out[1024 + k * DD + tid] = e;
  }
  __syncthreads();

  if (tid < DD) {
    float dd1 = s_c1[tid] - s_e[tid];
    float dd2 = s_c2[tid] - s_e[tid];
    float q1 = dd1 * dd1, q2 = dd2 * dd2;
#pragma unroll
    for (int off = 32; off > 0; off >>= 1) {
      q1 += __shfl_xor(q1, off);
      q2 += __shfl_xor(q2, off);
    }
    if (tid == 0) {
      out[512 + k] = sqrtf(q1);
      out[768 + k] = sqrtf(q2);
    }
  }

  if (tid == 0) {
    float dot = 0.f;
#pragma unroll
    for (int c = 0; c < DD; ++c) dot = fmaf(s_c1[c], s_c2[c], dot);
    float dsq = s_sq[i1] + s_sq[i2] - 2.0f * dot;
    float lw  = -sqrtf(fmaxf(dsq, 0.f));
    out[0   + k] = (float)i1;
    out[256 + k] = (float)i2;
    out[17408 + k] = lw + 0.69314718055994531f - s_lse;
    int ones = 0;
    for (int w = 0; w < 16; ++w) ones += s_onesw[w];
    ones -= (leaf[k * TT + i1] == 1) ? 1 : 0;
    ones -= (leaf[k * TT + i2] == 1) ? 1 : 0;
    int vminus = pN[0] - ones;
    out[17664 + k] = logf((float)vminus);
  }
}

extern "C" void kernel_launch(void* const* d_in, const int* in_sizes, int n_in,
                              void* d_out, int out_size, void* d_ws, size_t ws_size,
                              hipStream_t stream) {
  const int*   pN   = (const int*)d_in[0];
  const int*   leaf = (const int*)d_in[1];
  const float* emb  = (const float*)d_in[2];
  const float* W1   = (const float*)d_in[4];
  const float* b1   = (const float*)d_in[5];
  const float* W2   = (const float*)d_in[6];
  const float* b2   = (const float*)d_in[7];
  float* out = (float*)d_out;
  KWs*   ws  = (KWs*)d_ws;

  (void)hipMemsetAsync(d_ws, 0, TK * sizeof(KWs), stream);
  ep_fused<<<TK * 2, NTHREADS, 0, stream>>>(pN, leaf, emb, W1, b1, W2, b2, out, ws);
}